// Round 6
// baseline (29.111 us; speedup 1.0000x reference)
//
#include <hip/hip_runtime.h>

// Problem constants (match reference).
#define BB     64
#define NN     900
#define MM     300
#define NC1    92            // NUM_CLASSES + 1
#define MQ     75            // float4 groups per m-row (300/4)
#define KN     4             // n-rows per thread
#define TILE_N 20            // n-rows per block (5 chunks of KN)
#define NCHUNK (TILE_N / KN) // 5
#define NT     (NN / TILE_N) // 45 tiles
#define ACT    (NCHUNK * MQ) // 375 active compute threads
#define BD     384           // 6 waves

// LDS gt layout: groups of 4 boxes, 13 float4 per group (12 data + 1 pad).
// Per box j in group: [3j+0]=(gx,gy,gz,gw) [3j+1]=(gux,guy,gdx1,gdy1)
//                     [3j+2]=(gz1,gw1,ga,lbl_bits)
#define GT_GRP_F4 13

__global__ __launch_bounds__(BD) void cost_kernel(
    const float4* __restrict__ bbox_pred,   // [B*N]
    const float*  __restrict__ labels_pred, // [B*N*92]
    const float4* __restrict__ bbox_gt,     // [B*M]
    const int*    __restrict__ labels_gt,   // [B*M]
    float4*       __restrict__ out)         // [B*N*MQ]
{
    __shared__ float  lp_lds[TILE_N * NC1];           // 1840 floats = 7.36 KB
    __shared__ float4 gt_lds[(MM / 4) * GT_GRP_F4];   // 975 f4 = 15.6 KB

    const int b  = blockIdx.x / NT;
    const int nt = blockIdx.x % NT;
    const int n0 = nt * TILE_N;
    const int t  = threadIdx.x;

    // ---- Stage labels_pred tile rows (contiguous, coalesced) ----
    {
        const float4* src = (const float4*)(labels_pred + ((size_t)b * NN + n0) * NC1);
        float4* dst = (float4*)lp_lds;
        const int nf4 = TILE_N * NC1 / 4;             // 460
        for (int i = t; i < nf4; i += BD) dst[i] = src[i];
    }

    // ---- Stage all 300 gt boxes, pre-derived ----
    for (int i = t; i < MM; i += BD) {
        float4 g = bbox_gt[b * MM + i];
        int   lb = labels_gt[b * MM + i];
        float gux = g.x - 0.5f * g.z, guy = g.y - 0.5f * g.w;
        float gdx1 = g.x + 0.5f * g.z + 1.0f;
        float gdy1 = g.y + 0.5f * g.w + 1.0f;
        float gz1 = g.z + 1.0f, gw1 = g.w + 1.0f;
        float4* grp = &gt_lds[(i >> 2) * GT_GRP_F4 + (i & 3) * 3];
        grp[0] = make_float4(g.x, g.y, g.z, g.w);
        grp[1] = make_float4(gux, guy, gdx1, gdy1);
        grp[2] = make_float4(gz1, gw1, gz1 * gw1, __int_as_float(lb));
    }

    __syncthreads();

    if (t >= ACT) return;
    const int c   = t / MQ;          // chunk 0..4
    const int mq  = t % MQ;
    const int bn0 = b * NN + n0 + c * KN;
    const int row0 = c * KN;         // row index within tile (for lp_lds)

    // ---- p-state for KN rows (broadcast loads within chunk) ----
    float px[KN], py[KN], pzr[KN], pwr[KN];
    float pux[KN], puy[KN], pdx1[KN], pdy1[KN], pz1[KN], pw1[KN], parea[KN];
#pragma unroll
    for (int k = 0; k < KN; ++k) {
        float4 p = bbox_pred[bn0 + k];
        px[k] = p.x; py[k] = p.y; pzr[k] = p.z; pwr[k] = p.w;
        pux[k]  = p.x - 0.5f * p.z;  puy[k]  = p.y - 0.5f * p.w;
        pdx1[k] = p.x + 0.5f * p.z + 1.0f;
        pdy1[k] = p.y + 0.5f * p.w + 1.0f;
        pz1[k]  = p.z + 1.0f;        pw1[k]  = p.w + 1.0f;
        parea[k] = pz1[k] * pw1[k];
    }

    float res[KN][4];
    const float4* grp = &gt_lds[mq * GT_GRP_F4];

#pragma unroll
    for (int j = 0; j < 4; ++j) {
        float4 s0 = grp[j * 3 + 0];   // gx,gy,gz,gw
        float4 s1 = grp[j * 3 + 1];   // gux,guy,gdx1,gdy1
        float4 s2 = grp[j * 3 + 2];   // gz1,gw1,ga,lbl
        int lbl = __float_as_int(s2.w);

        float cls[KN];
#pragma unroll
        for (int k = 0; k < KN; ++k)
            cls[k] = lp_lds[(row0 + k) * NC1 + lbl];

#pragma unroll
        for (int k = 0; k < KN; ++k) {
            float iwrx = fminf(pdx1[k], s1.z) - fmaxf(pux[k], s1.x);
            float iwry = fminf(pdy1[k], s1.w) - fmaxf(puy[k], s1.y);
            float inter = fmaxf(iwrx, 0.0f) * fmaxf(iwry, 0.0f);

            // bound via sum identity: iw_raw + bw = (pz+1)+(gz+1)
            float bwx = (pz1[k] + s2.x) - iwrx;
            float bwy = (pw1[k] + s2.y) - iwry;
            float barea = bwx * bwy;

            float uni = (parea[k] + s2.z) - inter;
            float iou = inter * __builtin_amdgcn_rcpf(uni);
            float tt  = uni   * __builtin_amdgcn_rcpf(barea);   // bg = 1 - tt

            float bbox = fabsf(px[k] - s0.x) + fabsf(py[k] - s0.y)
                       + fabsf(pzr[k] - s0.z) + fabsf(pwr[k] - s0.w);

            res[k][j] = bbox + (1.0f - cls[k]) - tt - iou;
        }
    }

#pragma unroll
    for (int k = 0; k < KN; ++k)
        out[(size_t)(bn0 + k) * MQ + mq] =
            make_float4(res[k][0], res[k][1], res[k][2], res[k][3]);
}

extern "C" void kernel_launch(void* const* d_in, const int* in_sizes, int n_in,
                              void* d_out, int out_size, void* d_ws, size_t ws_size,
                              hipStream_t stream) {
    const float4* bbox_pred   = (const float4*)d_in[0];
    const float*  labels_pred = (const float*) d_in[1];
    const float4* bbox_gt     = (const float4*)d_in[2];
    const int*    labels_gt   = (const int*)   d_in[3];
    float4*       out         = (float4*)d_out;

    const int grid = BB * NT;                 // 2880 blocks
    cost_kernel<<<grid, BD, 0, stream>>>(bbox_pred, labels_pred, bbox_gt,
                                         labels_gt, out);
}